// Round 5
// baseline (88.502 us; speedup 1.0000x reference)
//
#include <hip/hip_runtime.h>
#include <hip/hip_bf16.h>

// Problem constants
#define B_ROWS 4096
#define NN     8192
#define DD     128
#define CSPLIT 16           // column splits (blocks per row-group)
#define NSPLIT (CSPLIT * 2) // wn adds another factor of 2
#define TSTEPS 8            // 128 pair-cols per wn-wave / 16 per t-step

typedef __attribute__((ext_vector_type(8))) short s8v;   // 8 bf16 (4 VGPR)
typedef __attribute__((ext_vector_type(4))) float f4v;   // 4 f32
typedef __attribute__((ext_vector_type(2))) float f2v;

static constexpr float SCALE_H = 1.6986436f;      // sqrt(2*log2(e)); folds /TEMP and log2e into the matmul
static constexpr float SCALE2  = 2.8853900818f;   // 2*log2(e)
static constexpr float LN2     = 0.6931471805599453f;
static constexpr float MASKVAL = -3.0e38f;
static constexpr float MINIT   = -1.0e30f;

__device__ __forceinline__ float fast_exp2(float x) {
#if __has_builtin(__builtin_amdgcn_exp2f)
    return __builtin_amdgcn_exp2f(x);      // bare v_exp_f32
#else
    return exp2f(x);
#endif
}

// ---- kernel 1: fused bf16-prep + pos dot ----
// 1024 blocks x 256 thr; wave w handles row = blk*4 + w of hi/hj.
// Writes hb[row] (from hi) and hb[row+B] (from hj), plus pos2[row].
__global__ void hpos_kernel(const float* __restrict__ hi, const float* __restrict__ hj,
                            __hip_bfloat16* __restrict__ hb, float* __restrict__ pos2) {
    int w = threadIdx.x >> 6, l = threadIdx.x & 63;
    int row = blockIdx.x * 4 + w;
    f2v a = ((const f2v*)(hi + (size_t)row * DD))[l];
    f2v b = ((const f2v*)(hj + (size_t)row * DD))[l];
    // pos dot in f32
    float d = a[0] * b[0] + a[1] * b[1];
    #pragma unroll
    for (int off = 32; off; off >>= 1) d += __shfl_xor(d, off, 64);
    if (l == 0) pos2[row] = SCALE2 * d;
    // scaled bf16 store (4B per lane, coalesced)
    union { ushort2 u2; __hip_bfloat16 h[2]; } ua, ub;
    ua.h[0] = __float2bfloat16(a[0] * SCALE_H);
    ua.h[1] = __float2bfloat16(a[1] * SCALE_H);
    ub.h[0] = __float2bfloat16(b[0] * SCALE_H);
    ub.h[1] = __float2bfloat16(b[1] * SCALE_H);
    ((ushort2*)(hb + (size_t)row * DD))[l] = ua.u2;
    ((ushort2*)(hb + (size_t)(row + B_ROWS) * DD))[l] = ub.u2;
}

// ---- kernel 2: fused sim*S2 + masked online logsumexp (log2 domain) ----
// Block: 256 thr = 4 waves, wave (wm,wn). Rows: {r0..r0+15} U {+B} (fm).
// Per t-step: 16 pair-cols {pc..pc+15} U {+B} (fh). One S value feeds 4 elems.
// S panel (32 rows x 256 cols, 32 KB) bulk-staged in LDS at block start;
// B-frags double-buffered in NAMED registers, prefetched one t-step ahead.
__global__ __launch_bounds__(256, 3)
void main_kernel(const __hip_bfloat16* __restrict__ hb, const float* __restrict__ S,
                 float* __restrict__ msplit, float* __restrict__ ssplit) {
    __shared__ float sS[32][256];        // 32 KB S panel

    const int tid = threadIdx.x;
    const int l  = tid & 63;
    const int w  = tid >> 6;
    const int wm = w >> 1, wn = w & 1;
    const int rb = blockIdx.x & 127;
    const int cs = blockIdx.x >> 7;
    const int r0 = rb * 32 + wm * 16;    // wave row base (first half)
    const int c0 = cs * 256;             // 256 pair-cols per block
    const int lc = l & 15;               // frag row/col within 16
    const int lk = l >> 4;               // k-group

    const s8v* hb8 = (const s8v*)hb;     // 16 x s8v per row of 128 bf16

    // ---- stage S panel: rows rb*32..+31, cols c0..+255 ----
    // iter it: wave w loads row it*4+w, 1 KB coalesced (16B/lane), then ds_write.
    f4v sreg[8];
    {
        const float* gS = S + (size_t)(rb * 32) * B_ROWS + c0;
        #pragma unroll
        for (int it = 0; it < 8; it++)
            sreg[it] = *(const f4v*)(gS + (size_t)(it * 4 + w) * B_ROWS + l * 4);
    }

    // A fragments (independent of S panel), issued while S loads fly
    s8v afr[2][4];
    #pragma unroll
    for (int fm = 0; fm < 2; fm++) {
        int ar = r0 + lc + fm * B_ROWS;
        #pragma unroll
        for (int kk = 0; kk < 4; kk++)
            afr[fm][kk] = hb8[ar * 16 + kk * 4 + lk];
    }

    #pragma unroll
    for (int it = 0; it < 8; it++)
        *(f4v*)(&sS[it * 4 + w][l * 4]) = sreg[it];
    __syncthreads();

    float m[2][4], ssum[2][4];
    #pragma unroll
    for (int fm = 0; fm < 2; fm++)
        #pragma unroll
        for (int r = 0; r < 4; r++) { m[fm][r] = MINIT; ssum[fm][r] = 0.f; }

    const int srowbase = r0 + lk * 4;    // global S row for (r)
    const int lrow = wm * 16 + lk * 4;   // panel-local row base

#define PCOL(T) (c0 + (T) * 32 + wn * 16)

#define LOADB(BF, T) do {                                                   \
    const int _pc = PCOL(T);                                                \
    _Pragma("unroll")                                                       \
    for (int fh = 0; fh < 2; fh++) {                                        \
        _Pragma("unroll")                                                   \
        for (int kk = 0; kk < 4; kk++)                                      \
            BF[fh][kk] = hb8[(_pc + lc + fh * B_ROWS) * 16 + kk * 4 + lk];  \
    }                                                                       \
} while (0)

#define COMPUTE(BF, T) do {                                                 \
    f4v acc[2][2];                                                          \
    _Pragma("unroll")                                                       \
    for (int fm = 0; fm < 2; fm++)                                          \
        _Pragma("unroll")                                                   \
        for (int fh = 0; fh < 2; fh++) acc[fm][fh] = f4v{0.f, 0.f, 0.f, 0.f};\
    _Pragma("unroll")                                                       \
    for (int kk = 0; kk < 4; kk++)                                          \
        _Pragma("unroll")                                                   \
        for (int fm = 0; fm < 2; fm++)                                      \
            _Pragma("unroll")                                               \
            for (int fh = 0; fh < 2; fh++)                                  \
                acc[fm][fh] = __builtin_amdgcn_mfma_f32_16x16x32_bf16(      \
                    afr[fm][kk], BF[fh][kk], acc[fm][fh], 0, 0, 0);         \
    const int _pc = PCOL(T);                                                \
    const int _lcol = (T) * 32 + wn * 16 + lc;                              \
    _Pragma("unroll")                                                       \
    for (int r = 0; r < 4; r++) {                                           \
        const bool msk = (_pc + lc == srowbase + r);                        \
        const float Sv = sS[lrow + r][_lcol];                               \
        const float s2 = 1.f - Sv * Sv;                                     \
        _Pragma("unroll")                                                   \
        for (int fm = 0; fm < 2; fm++) {                                    \
            float v0 = msk ? MASKVAL : acc[fm][0][r] * s2;                  \
            float v1 = msk ? MASKVAL : acc[fm][1][r] * s2;                  \
            float mo = m[fm][r];                                            \
            float nm = fmaxf(mo, fmaxf(v0, v1));                            \
            ssum[fm][r] = ssum[fm][r] * fast_exp2(mo - nm)                  \
                        + fast_exp2(v0 - nm) + fast_exp2(v1 - nm);          \
            m[fm][r] = nm;                                                  \
        }                                                                   \
    }                                                                       \
} while (0)

    // named ping-pong B buffers (static indexing only)
    s8v bA[2][4], bB[2][4];

    LOADB(bA, 0);
    for (int tt = 0; tt < TSTEPS; tt += 2) {
        LOADB(bB, tt + 1);
        COMPUTE(bA, tt);
        if (tt + 2 < TSTEPS) LOADB(bA, tt + 2);
        COMPUTE(bB, tt + 1);
    }

#undef PCOL
#undef LOADB
#undef COMPUTE

    // reduce (m,s) across the 16 lanes holding the same row, write per-split state
    #pragma unroll
    for (int fm = 0; fm < 2; fm++) {
        #pragma unroll
        for (int r = 0; r < 4; r++) {
            float mm = m[fm][r], ss = ssum[fm][r];
            #pragma unroll
            for (int off = 1; off < 16; off <<= 1) {
                float mo = __shfl_xor(mm, off, 64);
                float so = __shfl_xor(ss, off, 64);
                float nm = fmaxf(mm, mo);
                ss = ss * fast_exp2(mm - nm) + so * fast_exp2(mo - nm);
                mm = nm;
            }
            if (lc == 0) {
                int gr = srowbase + r + fm * B_ROWS;
                int sp = cs * 2 + wn;
                msplit[sp * NN + gr] = mm;
                ssplit[sp * NN + gr] = ss;
            }
        }
    }
}

// ---- kernel 3a: per-row split merge + lse, block partial sums (parallel) ----
__global__ __launch_bounds__(256)
void reduce_kernel(const float* __restrict__ msplit, const float* __restrict__ ssplit,
                   const float* __restrict__ pos2, float* __restrict__ partial) {
    __shared__ float red[256];
    const int n = blockIdx.x * 256 + threadIdx.x;   // n < 8192
    float p = pos2[n & (B_ROWS - 1)];
    float M = p, Ssum = 1.f;                        // pos logit seeds the lse
    #pragma unroll
    for (int sp = 0; sp < NSPLIT; sp++) {
        float mo = msplit[sp * NN + n];
        float so = ssplit[sp * NN + n];
        float nm = fmaxf(M, mo);
        Ssum = Ssum * fast_exp2(M - nm) + so * fast_exp2(mo - nm);
        M = nm;
    }
    red[threadIdx.x] = (M + log2f(Ssum)) - p;       // log2 units
    __syncthreads();
    for (int st = 128; st; st >>= 1) {
        if (threadIdx.x < st) red[threadIdx.x] += red[threadIdx.x + st];
        __syncthreads();
    }
    if (threadIdx.x == 0) partial[blockIdx.x] = red[0];
}

// ---- kernel 3b: deterministic final sum over 32 partials ----
__global__ void final_kernel(const float* __restrict__ partial, float* __restrict__ out) {
    if (threadIdx.x == 0) {
        float s = 0.f;
        #pragma unroll
        for (int i = 0; i < 32; i++) s += partial[i];
        out[0] = s * (LN2 / (float)NN);
    }
}

extern "C" void kernel_launch(void* const* d_in, const int* in_sizes, int n_in,
                              void* d_out, int out_size, void* d_ws, size_t ws_size,
                              hipStream_t stream) {
    (void)in_sizes; (void)n_in; (void)out_size; (void)ws_size;
    const float* hi = (const float*)d_in[0];
    const float* hj = (const float*)d_in[1];
    const float* S  = (const float*)d_in[2];

    char* ws = (char*)d_ws;
    __hip_bfloat16* hb = (__hip_bfloat16*)ws;                        // 2 MB
    float* pos2   = (float*)(ws + 2097152);                          // 16 KB
    float* msplit = (float*)(ws + 2097152 + 16384);                  // 1 MB (32 splits)
    float* ssplit = (float*)(ws + 2097152 + 16384 + 1048576);        // 1 MB
    float* partial= (float*)(ws + 2097152 + 16384 + 2 * 1048576);    // 128 B

    hpos_kernel<<<1024, 256, 0, stream>>>(hi, hj, hb, pos2);
    main_kernel<<<2048, 256, 0, stream>>>(hb, S, msplit, ssplit);
    reduce_kernel<<<32, 256, 0, stream>>>(msplit, ssplit, pos2, partial);
    final_kernel<<<1, 64, 0, stream>>>(partial, (float*)d_out);
}

// Round 6
// 71.154 us; speedup vs baseline: 1.2438x; 1.2438x over previous
//
#include <hip/hip_runtime.h>
#include <hip/hip_bf16.h>

// Problem constants
#define B_ROWS 4096
#define NN     8192
#define DD     128
#define NSPLIT 32           // column splits (= #cs blocks); merged across wn in LDS
#define TSTEPS 4            // 128 pair-cols per block / 32 per t-step

typedef __attribute__((ext_vector_type(8))) short s8v;   // 8 bf16 (4 VGPR)
typedef __attribute__((ext_vector_type(4))) float f4v;   // 4 f32
typedef __attribute__((ext_vector_type(2))) float f2v;

static constexpr float SCALE_H = 1.6986436f;      // sqrt(2*log2(e)); folds /TEMP and log2e into the matmul
static constexpr float SCALE2  = 2.8853900818f;   // 2*log2(e)
static constexpr float LN2     = 0.6931471805599453f;
static constexpr float MASKVAL = -3.0e38f;
static constexpr float MINIT   = -1.0e30f;

__device__ __forceinline__ float fast_exp2(float x) {
#if __has_builtin(__builtin_amdgcn_exp2f)
    return __builtin_amdgcn_exp2f(x);      // bare v_exp_f32
#else
    return exp2f(x);
#endif
}

typedef unsigned int u32;
typedef __attribute__((address_space(1))) const u32 gu32;
typedef __attribute__((address_space(3))) u32 lu32;
__device__ __forceinline__ void gload_lds16(const void* g, void* l) {
    // async global->LDS, 16B/lane; dest = lds base + lane*16 (wave-uniform base)
    __builtin_amdgcn_global_load_lds((gu32*)g, (lu32*)l, 16, 0, 0);
}

// ---- kernel 1: fused bf16-prep + pos dot ----
__global__ void hpos_kernel(const float* __restrict__ hi, const float* __restrict__ hj,
                            __hip_bfloat16* __restrict__ hb, float* __restrict__ pos2) {
    int w = threadIdx.x >> 6, l = threadIdx.x & 63;
    int row = blockIdx.x * 4 + w;
    f2v a = ((const f2v*)(hi + (size_t)row * DD))[l];
    f2v b = ((const f2v*)(hj + (size_t)row * DD))[l];
    float d = a[0] * b[0] + a[1] * b[1];
    #pragma unroll
    for (int off = 32; off; off >>= 1) d += __shfl_xor(d, off, 64);
    if (l == 0) pos2[row] = SCALE2 * d;
    union { ushort2 u2; __hip_bfloat16 h[2]; } ua, ub;
    ua.h[0] = __float2bfloat16(a[0] * SCALE_H);
    ua.h[1] = __float2bfloat16(a[1] * SCALE_H);
    ub.h[0] = __float2bfloat16(b[0] * SCALE_H);
    ub.h[1] = __float2bfloat16(b[1] * SCALE_H);
    ((ushort2*)(hb + (size_t)row * DD))[l] = ua.u2;
    ((ushort2*)(hb + (size_t)(row + B_ROWS) * DD))[l] = ub.u2;
}

// ---- kernel 2: fused sim*S2 + masked online logsumexp (log2 domain) ----
// Grid 4096 = 128 rb x 32 cs. Block: 32 pair-rows x 128 pair-cols, 4 waves (wm,wn).
// Per t-step: B tile (32 pair-cols x 2 halves = 64 hb-rows, 16 KB) staged via
// global_load_lds into double-buffered LDS (linear dest, source pre-swizzled by
// c16 ^= row&7; same XOR on ds_read -> conflict-free b128). STAGE(t+1) issued
// before COMPUTE(t); one __syncthreads per t-step (m97 2-phase schedule).
__global__ __launch_bounds__(256, 3)
void main_kernel(const __hip_bfloat16* __restrict__ hb, const float* __restrict__ S,
                 float* __restrict__ msplit, float* __restrict__ ssplit) {
    __shared__ short ldsB[2][64][128];            // 2 x 16 KB B tiles (swizzled)
    __shared__ float sS[32][132];                 // 16.5 KB S panel (padded)
    __shared__ float mex[2][2][32], sex[2][2][32];// 1 KB wn-merge

    const int tid = threadIdx.x;
    const int l  = tid & 63;
    const int w  = tid >> 6;
    const int wm = w >> 1, wn = w & 1;
    const int rb = blockIdx.x & 127;
    const int cs = blockIdx.x >> 7;
    const int r0 = rb * 32 + wm * 16;    // wave pair-row base
    const int c0 = cs * 128;             // block pair-col base
    const int lc = l & 15;               // frag row/col within 16
    const int lk = l >> 4;               // k-group

    const s8v* hb8 = (const s8v*)hb;     // 16 x s8v per row of 128 bf16

#define STAGE(BUF, T) do {                                                        \
    _Pragma("unroll")                                                             \
    for (int i = 0; i < 4; i++) {                                                 \
        const int seg  = w * 4 + i;                                               \
        const int lrw  = seg * 4 + lk;     /* local row 0..63 */                  \
        const int grow = c0 + (T) * 32 + ((lrw < 32) ? lrw : (lrw - 32 + B_ROWS));\
        const int sc16 = lc ^ (lrw & 7);   /* source pre-swizzle */               \
        gload_lds16((const char*)hb + ((size_t)grow << 8) + (sc16 << 4),          \
                    (char*)&ldsB[BUF][seg * 4][0]);                               \
    }                                                                             \
} while (0)

    // prologue: stage tile 0, stage S panel (reg-staged), load A frags
    STAGE(0, 0);

    f4v sv0, sv1, sv2, sv3;
    {
        const int srow = tid >> 5;          // 0..7
        const int sc16 = tid & 31;
        const float* gS = S + (size_t)(rb * 32 + srow) * B_ROWS + c0 + sc16 * 4;
        sv0 = *(const f4v*)(gS);
        sv1 = *(const f4v*)(gS + (size_t)8 * B_ROWS);
        sv2 = *(const f4v*)(gS + (size_t)16 * B_ROWS);
        sv3 = *(const f4v*)(gS + (size_t)24 * B_ROWS);
    }

    s8v afr[2][4];
    #pragma unroll
    for (int fm = 0; fm < 2; fm++) {
        int ar = r0 + lc + fm * B_ROWS;
        #pragma unroll
        for (int kk = 0; kk < 4; kk++)
            afr[fm][kk] = hb8[ar * 16 + kk * 4 + lk];
    }

    {
        const int srow = tid >> 5;
        const int sc16 = tid & 31;
        *(f4v*)&sS[srow][sc16 * 4]      = sv0;
        *(f4v*)&sS[srow + 8][sc16 * 4]  = sv1;
        *(f4v*)&sS[srow + 16][sc16 * 4] = sv2;
        *(f4v*)&sS[srow + 24][sc16 * 4] = sv3;
    }
    __syncthreads();   // S panel + B tile 0 ready

    float m[2][4], ssum[2][4];
    #pragma unroll
    for (int fm = 0; fm < 2; fm++)
        #pragma unroll
        for (int r = 0; r < 4; r++) { m[fm][r] = MINIT; ssum[fm][r] = 0.f; }

    // loop-invariant ds_read addresses: base + (BUF*16384 + fh*8192) immediates
    const char* bp[4];
    {
        const char* bb = (const char*)ldsB + (wn * 16 + lc) * 256;
        #pragma unroll
        for (int kk = 0; kk < 4; kk++)
            bp[kk] = bb + (((kk * 4 + lk) ^ (lc & 7)) << 4);
    }

#define COMPUTE(BUF, T) do {                                                      \
    f4v acc[2][2];                                                                \
    _Pragma("unroll")                                                             \
    for (int fm = 0; fm < 2; fm++)                                                \
        _Pragma("unroll")                                                         \
        for (int fh = 0; fh < 2; fh++) acc[fm][fh] = f4v{0.f, 0.f, 0.f, 0.f};     \
    _Pragma("unroll")                                                             \
    for (int kk = 0; kk < 4; kk++) {                                              \
        s8v bf0 = *(const s8v*)(bp[kk] + ((BUF) * 16384));                        \
        s8v bf1 = *(const s8v*)(bp[kk] + ((BUF) * 16384 + 8192));                 \
        _Pragma("unroll")                                                         \
        for (int fm = 0; fm < 2; fm++) {                                          \
            acc[fm][0] = __builtin_amdgcn_mfma_f32_16x16x32_bf16(                 \
                afr[fm][kk], bf0, acc[fm][0], 0, 0, 0);                           \
            acc[fm][1] = __builtin_amdgcn_mfma_f32_16x16x32_bf16(                 \
                afr[fm][kk], bf1, acc[fm][1], 0, 0, 0);                           \
        }                                                                         \
    }                                                                             \
    const int lcol = (T) * 32 + wn * 16 + lc;                                     \
    const int scol = c0 + lcol;                                                   \
    _Pragma("unroll")                                                             \
    for (int r = 0; r < 4; r++) {                                                 \
        const int prow = wm * 16 + lk * 4 + r;                                    \
        const float Sv = sS[prow][lcol];                                          \
        const float s2 = 1.f - Sv * Sv;                                           \
        const bool msk = (scol == rb * 32 + prow);                                \
        _Pragma("unroll")                                                         \
        for (int fm = 0; fm < 2; fm++) {                                          \
            float v0 = msk ? MASKVAL : acc[fm][0][r] * s2;                        \
            float v1 = msk ? MASKVAL : acc[fm][1][r] * s2;                        \
            float mo = m[fm][r];                                                  \
            float nm = fmaxf(mo, fmaxf(v0, v1));                                  \
            ssum[fm][r] = ssum[fm][r] * fast_exp2(mo - nm)                        \
                        + fast_exp2(v0 - nm) + fast_exp2(v1 - nm);                \
            m[fm][r] = nm;                                                        \
        }                                                                         \
    }                                                                             \
} while (0)

    // 2-phase pipeline: stage next tile, compute current, barrier
    STAGE(1, 1); COMPUTE(0, 0); __syncthreads();
    STAGE(0, 2); COMPUTE(1, 1); __syncthreads();
    STAGE(1, 3); COMPUTE(0, 2); __syncthreads();
                 COMPUTE(1, 3);

#undef STAGE
#undef COMPUTE

    // lane-reduce (m,s) over the 16 lanes holding each row, then merge wn in LDS
    #pragma unroll
    for (int fm = 0; fm < 2; fm++) {
        #pragma unroll
        for (int r = 0; r < 4; r++) {
            float mm = m[fm][r], ss = ssum[fm][r];
            #pragma unroll
            for (int off = 1; off < 16; off <<= 1) {
                float mo = __shfl_xor(mm, off, 64);
                float so = __shfl_xor(ss, off, 64);
                float nm = fmaxf(mm, mo);
                ss = ss * fast_exp2(mm - nm) + so * fast_exp2(mo - nm);
                mm = nm;
            }
            if (lc == 0) {
                int rho = wm * 16 + lk * 4 + r;   // block-local pair-row
                mex[wn][fm][rho] = mm;
                sex[wn][fm][rho] = ss;
            }
        }
    }
    __syncthreads();
    if (tid < 64) {
        int fm = tid >> 5, rho = tid & 31;
        float m0 = mex[0][fm][rho], s0 = sex[0][fm][rho];
        float m1 = mex[1][fm][rho], s1 = sex[1][fm][rho];
        float nm = fmaxf(m0, m1);
        float ss = s0 * fast_exp2(m0 - nm) + s1 * fast_exp2(m1 - nm);
        int gr = rb * 32 + rho + fm * B_ROWS;
        msplit[cs * NN + gr] = nm;
        ssplit[cs * NN + gr] = ss;
    }
}

// ---- kernel 3a: per-row split merge + lse, block partial sums (parallel) ----
__global__ __launch_bounds__(256)
void reduce_kernel(const float* __restrict__ msplit, const float* __restrict__ ssplit,
                   const float* __restrict__ pos2, float* __restrict__ partial) {
    __shared__ float red[256];
    const int n = blockIdx.x * 256 + threadIdx.x;   // n < 8192
    float p = pos2[n & (B_ROWS - 1)];
    float M = p, Ssum = 1.f;                        // pos logit seeds the lse
    #pragma unroll
    for (int sp = 0; sp < NSPLIT; sp++) {
        float mo = msplit[sp * NN + n];
        float so = ssplit[sp * NN + n];
        float nm = fmaxf(M, mo);
        Ssum = Ssum * fast_exp2(M - nm) + so * fast_exp2(mo - nm);
        M = nm;
    }
    red[threadIdx.x] = (M + log2f(Ssum)) - p;       // log2 units
    __syncthreads();
    for (int st = 128; st; st >>= 1) {
        if (threadIdx.x < st) red[threadIdx.x] += red[threadIdx.x + st];
        __syncthreads();
    }
    if (threadIdx.x == 0) partial[blockIdx.x] = red[0];
}

// ---- kernel 3b: deterministic final sum over 32 partials ----
__global__ void final_kernel(const float* __restrict__ partial, float* __restrict__ out) {
    if (threadIdx.x == 0) {
        float s = 0.f;
        #pragma unroll
        for (int i = 0; i < 32; i++) s += partial[i];
        out[0] = s * (LN2 / (float)NN);
    }
}

extern "C" void kernel_launch(void* const* d_in, const int* in_sizes, int n_in,
                              void* d_out, int out_size, void* d_ws, size_t ws_size,
                              hipStream_t stream) {
    (void)in_sizes; (void)n_in; (void)out_size; (void)ws_size;
    const float* hi = (const float*)d_in[0];
    const float* hj = (const float*)d_in[1];
    const float* S  = (const float*)d_in[2];

    char* ws = (char*)d_ws;
    __hip_bfloat16* hb = (__hip_bfloat16*)ws;                        // 2 MB
    float* pos2   = (float*)(ws + 2097152);                          // 16 KB
    float* msplit = (float*)(ws + 2097152 + 16384);                  // 1 MB (32 splits)
    float* ssplit = (float*)(ws + 2097152 + 16384 + 1048576);        // 1 MB
    float* partial= (float*)(ws + 2097152 + 16384 + 2 * 1048576);    // 128 B

    hpos_kernel<<<1024, 256, 0, stream>>>(hi, hj, hb, pos2);
    main_kernel<<<4096, 256, 0, stream>>>(hb, S, msplit, ssplit);
    reduce_kernel<<<32, 256, 0, stream>>>(msplit, ssplit, pos2, partial);
    final_kernel<<<1, 64, 0, stream>>>(partial, (float*)d_out);
}